// Round 11
// baseline (338.158 us; speedup 1.0000x reference)
//
#include <hip/hip_runtime.h>

#define Nn 50000
#define Ee 800000
#define Gg 1000
#define Hh 128
#define Cc 6
#define EPSf 1e-5f
#define SB 1024                       // elements per scan block
#define NSB ((Nn + SB - 1) / SB)      // 49
#define NBH 64                        // histogram blocks
#define EPB (Ee / NBH)                // 12500 edges per histogram block
#define NW (Nn / 2)                   // 25000 packed u16-pair words
#define HWH (NW / 2)                  // 12500 words per half-pass (50 KB LDS)
#define GT ((Nn + 63) / 64)           // 782 gemm tiles
#define GT4 ((GT + 3) / 4)            // 196 four-tile gemm groups
#define NREP 8                        // stats atomic-spread replicas
#define STS (NREP * 2 * Hh)           // 2048 floats per layer's stats slab
#define NGB (Nn / 4)                  // 12500 gather blocks per half

typedef unsigned short u16;
typedef unsigned int u32;
typedef __attribute__((ext_vector_type(8))) short bf16x8;
typedef __attribute__((ext_vector_type(4))) float f32x4;
typedef __attribute__((ext_vector_type(4))) unsigned int u32x4;

static __device__ inline u16 f2bf(float f) {
    u32 u = __float_as_uint(f);
    u32 r = (u + 0x7fffu + ((u >> 16) & 1u)) >> 16;   // RNE
    return (u16)r;
}
static __device__ inline float bf_lo(u32 v) { return __uint_as_float(v << 16); }
static __device__ inline float bf_hi(u32 v) { return __uint_as_float(v & 0xffff0000u); }
static __device__ inline u32 pack2(float a, float b) {
    return ((u32)f2bf(b) << 16) | (u32)f2bf(a);
}

// ============ fused prologue: {hist} || {layer-0 GEMM (+W0 transpose)} || {WT1/WT2 + stats zero} ============
__global__ __launch_bounds__(1024) void k_pro(const int* __restrict__ ei_dst,
                                              u16* __restrict__ rankL,
                                              u32* __restrict__ partials,
                                              const float* __restrict__ Xf,
                                              const float* __restrict__ W3,
                                              u16* __restrict__ WT3,
                                              float* __restrict__ stats3,
                                              u16* __restrict__ Yh) {
    extern __shared__ __align__(16) unsigned char smem[];   // 50000 B dynamic
    int bid = blockIdx.x, tid = threadIdx.x;

    if (bid < NBH) {
        // ---- histogram branch (1024 threads) ----
        u32* h = (u32*)smem;          // HWH words (50 KB)
        int e0 = bid * EPB;
        u32* P = partials + bid * NW;
#pragma unroll 1
        for (int half = 0; half < 2; half++) {
            int wlo = half * HWH;
            for (int i = tid; i < HWH; i += 1024) h[i] = 0u;
            __syncthreads();
            for (int i = tid; i < EPB; i += 1024) {
                int d = ei_dst[e0 + i];
                int w = d >> 1;
                if (w >= wlo && w < wlo + HWH) {
                    u32 old = atomicAdd(&h[w - wlo], (d & 1) ? 65536u : 1u);
                    rankL[e0 + i] = (u16)((d & 1) ? (old >> 16) : (old & 0xffffu));
                }
            }
            __syncthreads();
            for (int i = tid; i < HWH; i += 1024) P[wlo + i] = h[i];
            __syncthreads();
        }
        return;
    }

    if (bid >= NBH + GT4) {
        // ---- WT1/WT2 transpose + stats zero branch ----
        int l = bid - (NBH + GT4) + 1;          // 1 or 2
        u16* tb = (u16*)smem;
        const float* W = W3 + l * Hh * Hh;
        u16* WTl = WT3 + l * Hh * Hh;
#pragma unroll
        for (int i = 0; i < 4; i++) {
            int v = tid + 1024 * i;             // float4 idx over 4096
            int r = v >> 5, c4 = v & 31;
            float4 d = ((const float4*)W)[v];
            u16* p = tb + r * 136 + c4 * 4;
            p[0] = f2bf(d.x); p[1] = f2bf(d.y); p[2] = f2bf(d.z); p[3] = f2bf(d.w);
        }
        if (l == 1) {
#pragma unroll
            for (int i = 0; i < 6; i++) {       // 3*STS = 6144 floats
                int idx = tid + 1024 * i;
                stats3[idx] = 0.0f;
            }
        }
        __syncthreads();
#pragma unroll
        for (int i = 0; i < 16; i++) {
            int o = tid + 1024 * i;             // u16 idx over 16384
            int n = o >> 7, k = o & 127;
            WTl[o] = tb[k * 136 + n];
        }
        return;
    }

    // ---- layer-0 GEMM branch: in-block W0 transpose, 4 tiles/block ----
    u16* wt = (u16*)smem;             // Hh*136 u16 = 34816 B
#pragma unroll
    for (int i = 0; i < 4; i++) {
        int v = tid + 1024 * i;       // float4 idx over 4096: W0[k][n0..n0+3]
        int k = v >> 5, n0 = (v & 31) << 2;
        float4 d = ((const float4*)W3)[v];
        wt[(n0 + 0) * 136 + k] = f2bf(d.x);
        wt[(n0 + 1) * 136 + k] = f2bf(d.y);
        wt[(n0 + 2) * 136 + k] = f2bf(d.z);
        wt[(n0 + 3) * 136 + k] = f2bf(d.w);
    }
    __syncthreads();

    int tile = (bid - NBH) * 4 + (tid >> 8);
    if (tile >= GT) return;
    int t256 = tid & 255;
    int wv = t256 >> 6, lane = t256 & 63;
    int m = lane & 15, q = lane >> 4;
    int row0 = tile * 64 + wv * 16;
    int lrow = row0 + m;
    if (lrow >= Nn) lrow = Nn - 1;    // clamp load row; stores guarded
    const float* xfrow = Xf + lrow * Hh + q * 8;

    f32x4 acc[8] = {};
#pragma unroll
    for (int k0 = 0; k0 < Hh; k0 += 32) {
        float4 u0 = *(const float4*)(xfrow + k0);
        float4 u1 = *(const float4*)(xfrow + k0 + 4);
        union { bf16x8 v; u32 u[4]; } cv;
        cv.u[0] = pack2(u0.x, u0.y);
        cv.u[1] = pack2(u0.z, u0.w);
        cv.u[2] = pack2(u1.x, u1.y);
        cv.u[3] = pack2(u1.z, u1.w);
        bf16x8 a = cv.v;
#pragma unroll
        for (int t = 0; t < 8; t++) {
            bf16x8 b = *(const bf16x8*)(wt + (t * 16 + m) * 136 + k0 + q * 8);
            acc[t] = __builtin_amdgcn_mfma_f32_16x16x32_bf16(a, b, acc[t], 0, 0, 0);
        }
    }

    int orow0 = row0 + q * 4;
#pragma unroll
    for (int t = 0; t < 8; t++) {
#pragma unroll
        for (int r = 0; r < 4; r++) {
            int rr = orow0 + r;
            if (rr < Nn) Yh[rr * Hh + t * 16 + m] = f2bf(acc[t][r]);
        }
    }
}

// ---------------- scan phase 1 (fused partials merge) + dis + gstart ----------------
__global__ __launch_bounds__(256) void k_scan1(const u32* __restrict__ partials,
                                               u32* __restrict__ base_off,
                                               int* __restrict__ rs,
                                               int* __restrict__ bsum,
                                               float* __restrict__ dis,
                                               const int* __restrict__ batch,
                                               int* __restrict__ gstart) {
    __shared__ int ts[256];
    int b = blockIdx.x;
    int t = threadIdx.x;
    int base = b * SB + t * 4;        // 4 nodes = 2 packed words
    int v[4] = {0, 0, 0, 0};
    if (base < Nn) {                  // Nn%4==0 so whole quad in-bounds
        int w0 = base >> 1;
        u32 run0 = 0, run1 = 0;
#pragma unroll 8
        for (int b2 = 0; b2 < NBH; b2++) {
            u32 p0 = partials[b2 * NW + w0];
            u32 p1 = partials[b2 * NW + w0 + 1];
            base_off[b2 * NW + w0] = run0;
            base_off[b2 * NW + w0 + 1] = run1;
            run0 += p0; run1 += p1;
        }
        v[0] = (int)(run0 & 0xffffu); v[1] = (int)(run0 >> 16);
        v[2] = (int)(run1 & 0xffffu); v[3] = (int)(run1 >> 16);
        dis[base]     = rsqrtf((float)v[0] + 1.0f);
        dis[base + 1] = rsqrtf((float)v[1] + 1.0f);
        dis[base + 2] = rsqrtf((float)v[2] + 1.0f);
        dis[base + 3] = rsqrtf((float)v[3] + 1.0f);
    }
    int g = b * 256 + t;
    if (g <= Gg) {
        int lo = 0, hi = Nn;
        while (lo < hi) {
            int mid = (lo + hi) >> 1;
            if (batch[mid] < g) lo = mid + 1; else hi = mid;
        }
        gstart[g] = lo;
    }
    int tsum = v[0] + v[1] + v[2] + v[3];
    ts[t] = tsum;
    __syncthreads();
    for (int off = 1; off < 256; off <<= 1) {
        int x = (t >= off) ? ts[t - off] : 0;
        __syncthreads();
        ts[t] += x;
        __syncthreads();
    }
    int run = (t == 0) ? 0 : ts[t - 1];
    if (t == 255) {
        bsum[b] = ts[255];
        if (b == NSB - 1) rs[Nn] = ts[255];   // local end of last block
    }
#pragma unroll
    for (int j = 0; j < 4; j++) {
        int i = base + j;
        if (i < Nn) { rs[i] = run; run += v[j]; }
    }
}

// ---------------- counting-sort fill (absorbs scan2): ATOMIC-FREE ----------------
__global__ __launch_bounds__(256) void k_fill(const int* __restrict__ ei,
                                              const int* __restrict__ rs,
                                              const int* __restrict__ bsum,
                                              int* __restrict__ rs2,
                                              const u16* __restrict__ rankL,
                                              const u32* __restrict__ base_off,
                                              const float* __restrict__ dis,
                                              u32* __restrict__ recs) {
    __shared__ int lboff[NSB];
    int t = threadIdx.x;
    if (t < 64) {
        int orig = (t < NSB) ? bsum[t] : 0;
        int v = orig;
#pragma unroll
        for (int off = 1; off < 64; off <<= 1) {
            int u = __shfl_up(v, off, 64);
            if (t >= off) v += u;
        }
        if (t < NSB) lboff[t] = v - orig;   // exclusive over scan blocks
    }
    __syncthreads();

    int gi = blockIdx.x * 256 + t;
    if (gi <= Nn) rs2[gi] = rs[gi] + lboff[gi >> 10];   // blocks 0..195 active here

    int e = gi;
    if (e >= Ee) return;
    int s = ei[e];
    int d = ei[Ee + e];
    int blk = e / EPB;
    u32 bo = base_off[blk * NW + (d >> 1)];
    int rank = (int)rankL[e] + (int)((d & 1) ? (bo >> 16) : (bo & 0xffffu));
    int slot = rs[d] + lboff[d >> 10] + rank;
    float w = dis[s] * dis[d];
    recs[slot] = ((u32)f2bf(w) << 16) | (u32)s;   // s < 50000 < 65536
}

// ---------------- CSR gather: channel-split 2-pass, 8 edges per dwordx4 load ----------------
// half = bid / NGB selects 128 B half-rows -> per-pass working set 6.4 MB
// (vs 12.8), raising per-XCD L2 hit ~31%->~62% and halving L3 traffic.
// Lane map: lg=lane>>3 edge slot (8 edges/instr), lc=lane&7 uint4 col in half-row.
// Dispatch order separates the two halves temporally (~92%).
__global__ __launch_bounds__(256) void k_gather(const u16* __restrict__ Yh,
                                                const float* __restrict__ dis,
                                                const float* __restrict__ bias,
                                                const int* __restrict__ rs2,
                                                const u32* __restrict__ recs,
                                                u16* __restrict__ Ah) {
    int bh = blockIdx.x;
    int half = bh / NGB;              // 0 or 1
    int node = (bh - half * NGB) * 4 + (threadIdx.x >> 6);
    if (node >= Nn) return;
    int lane = threadIdx.x & 63;
    int lg = lane >> 3;               // edge slot within octet
    int lc = lane & 7;                // uint4 column within 128B half-row

    const uint4* rows4 = (const uint4*)Yh;    // full row = 16 uint4 = 256 B
    int hoff = half * 8;                      // half-row offset in uint4

    float acc[8] = {0.f, 0.f, 0.f, 0.f, 0.f, 0.f, 0.f, 0.f};

    int beg = rs2[node];
    int end = rs2[node + 1];

    for (int base = beg; base < end; base += 64) {
        int me = base + lane;
        u32 myrec = __builtin_nontemporal_load(recs + (me < end ? me : end - 1));
        int cnt = end - base;
        if (cnt > 64) cnt = 64;
        for (int i0 = 0; i0 < cnt; i0 += 32) {
            u32 rr[4]; float ww[4]; uint4 vv[4];
#pragma unroll
            for (int j = 0; j < 4; j++) {
                int si = i0 + j * 8 + lg;
                int sc = si < cnt ? si : cnt - 1;
                u32 rec = __shfl(myrec, sc, 64);
                rr[j] = rec & 0xffffu;
                ww[j] = (si < cnt) ? __uint_as_float(rec & 0xffff0000u) : 0.0f;
            }
#pragma unroll
            for (int j = 0; j < 4; j++) vv[j] = rows4[rr[j] * 16 + hoff + lc];
#pragma unroll
            for (int j = 0; j < 4; j++) {
                acc[0] += bf_lo(vv[j].x) * ww[j];
                acc[1] += bf_hi(vv[j].x) * ww[j];
                acc[2] += bf_lo(vv[j].y) * ww[j];
                acc[3] += bf_hi(vv[j].y) * ww[j];
                acc[4] += bf_lo(vv[j].z) * ww[j];
                acc[5] += bf_hi(vv[j].z) * ww[j];
                acc[6] += bf_lo(vv[j].w) * ww[j];
                acc[7] += bf_hi(vv[j].w) * ww[j];
            }
        }
    }
#pragma unroll
    for (int k = 0; k < 8; k++) {
        acc[k] += __shfl_xor(acc[k], 8, 64);
        acc[k] += __shfl_xor(acc[k], 16, 64);
        acc[k] += __shfl_xor(acc[k], 32, 64);
    }
    if (lg == 0) {                    // lanes 0..7 write one 128 B half-row
        float sn = dis[node];
        sn = sn * sn;
        uint4 hv = rows4[node * 16 + hoff + lc];
        const float4* bq = (const float4*)bias;
        float4 b0 = bq[half * 16 + lc * 2];
        float4 b1 = bq[half * 16 + lc * 2 + 1];
        acc[0] = acc[0] + bf_lo(hv.x) * sn + b0.x;
        acc[1] = acc[1] + bf_hi(hv.x) * sn + b0.y;
        acc[2] = acc[2] + bf_lo(hv.y) * sn + b0.z;
        acc[3] = acc[3] + bf_hi(hv.y) * sn + b0.w;
        acc[4] = acc[4] + bf_lo(hv.z) * sn + b1.x;
        acc[5] = acc[5] + bf_hi(hv.z) * sn + b1.y;
        acc[6] = acc[6] + bf_lo(hv.w) * sn + b1.z;
        acc[7] = acc[7] + bf_hi(hv.w) * sn + b1.w;
        u32x4 o;
        o.x = pack2(acc[0], acc[1]);
        o.y = pack2(acc[2], acc[3]);
        o.z = pack2(acc[4], acc[5]);
        o.w = pack2(acc[6], acc[7]);
        __builtin_nontemporal_store(o, (u32x4*)Ah + node * 16 + hoff + lc);
    }
}

// ---------------- BN stats: per-channel sum & sumsq, 8-way replica atomic spread ----------------
__global__ __launch_bounds__(256) void k_stats(const u16* __restrict__ Ah,
                                               float* __restrict__ stats) {
    __shared__ float sh[4][256];
    int t = threadIdx.x;
    int jc = t & 63, ro = t >> 6;         // jc: u32-column (channels 2jc,2jc+1)
    const u32* col = (const u32*)Ah + jc;
    float sx = 0.f, sy = 0.f, qx = 0.f, qy = 0.f;
    for (int r = blockIdx.x * 16 + ro * 4; r < Nn; r += 4096) {
        u32 v[4];
#pragma unroll
        for (int k = 0; k < 4; k++) {
            int rr = r + k;
            v[k] = (rr < Nn) ? col[rr * 64] : 0u;
        }
#pragma unroll
        for (int k = 0; k < 4; k++) {
            float a = bf_lo(v[k]), b = bf_hi(v[k]);
            sx += a; sy += b; qx += a * a; qy += b * b;
        }
    }
    sh[0][t] = sx; sh[1][t] = sy; sh[2][t] = qx; sh[3][t] = qy;
    __syncthreads();
    if (t < 64) {
        sx = sh[0][t] + sh[0][t + 64] + sh[0][t + 128] + sh[0][t + 192];
        sy = sh[1][t] + sh[1][t + 64] + sh[1][t + 128] + sh[1][t + 192];
        qx = sh[2][t] + sh[2][t + 64] + sh[2][t + 128] + sh[2][t + 192];
        qy = sh[3][t] + sh[3][t + 64] + sh[3][t + 128] + sh[3][t + 192];
        float* rep = stats + (blockIdx.x & (NREP - 1)) * 2 * Hh;   // spread RMW lines 8x
        atomicAdd(&rep[2 * t], sx);
        atomicAdd(&rep[2 * t + 1], sy);
        atomicAdd(&rep[Hh + 2 * t], qx);
        atomicAdd(&rep[Hh + 2 * t + 1], qy);
    }
}

// ---------------- MFMA GEMM, fused BN-normalize+ReLU on A (layers 1,2) ----------------
__global__ __launch_bounds__(256) void k_gemm(const u16* __restrict__ Xin,
                                              const u16* __restrict__ WT,
                                              u16* __restrict__ Yh,
                                              const float* __restrict__ stats,
                                              const float* __restrict__ gam,
                                              const float* __restrict__ bet) {
    __shared__ u16 wt[Hh * 136];
    __shared__ float s_scale[Hh], s_shift[Hh];
    int tid = threadIdx.x;

    if (tid < Hh) {
        float s0 = 0.f, s1 = 0.f;
#pragma unroll
        for (int r = 0; r < NREP; r++) {          // sum replica slabs
            s0 += stats[r * 2 * Hh + tid];
            s1 += stats[r * 2 * Hh + Hh + tid];
        }
        float mu = s0 * (1.0f / Nn);
        float var = s1 * (1.0f / Nn) - mu * mu;
        float sc = rsqrtf(var + EPSf) * gam[tid];
        s_scale[tid] = sc;
        s_shift[tid] = bet[tid] - mu * sc;
    }
#pragma unroll
    for (int i = 0; i < 8; i++) {
        int v = tid + 256 * i;            // uint4 idx over 2048
        int n = v >> 4, k8 = v & 15;
        uint4 d = ((const uint4*)WT)[v];
        *((uint4*)(wt + n * 136 + k8 * 8)) = d;
    }
    __syncthreads();

    int wv = tid >> 6, lane = tid & 63;
    int m = lane & 15, q = lane >> 4;
    int row0 = blockIdx.x * 64 + wv * 16;
    int lrow = row0 + m;
    if (lrow >= Nn) lrow = Nn - 1;        // clamp load row; stores guarded
    const u16* xrow = Xin + lrow * Hh + q * 8;

    f32x4 acc[8] = {};
#pragma unroll
    for (int k0 = 0; k0 < Hh; k0 += 32) {
        int cb = k0 + q * 8;
        uint4 p = *(const uint4*)(xrow + k0);
        float4 sc0 = *(const float4*)(s_scale + cb);
        float4 sc1 = *(const float4*)(s_scale + cb + 4);
        float4 sh0 = *(const float4*)(s_shift + cb);
        float4 sh1 = *(const float4*)(s_shift + cb + 4);
        float f0 = fmaxf(bf_lo(p.x) * sc0.x + sh0.x, 0.0f);
        float f1 = fmaxf(bf_hi(p.x) * sc0.y + sh0.y, 0.0f);
        float f2 = fmaxf(bf_lo(p.y) * sc0.z + sh0.z, 0.0f);
        float f3 = fmaxf(bf_hi(p.y) * sc0.w + sh0.w, 0.0f);
        float f4 = fmaxf(bf_lo(p.z) * sc1.x + sh1.x, 0.0f);
        float f5 = fmaxf(bf_hi(p.z) * sc1.y + sh1.y, 0.0f);
        float f6 = fmaxf(bf_lo(p.w) * sc1.z + sh1.z, 0.0f);
        float f7 = fmaxf(bf_hi(p.w) * sc1.w + sh1.w, 0.0f);
        union { bf16x8 v; u32 u[4]; } cv;
        cv.u[0] = pack2(f0, f1);
        cv.u[1] = pack2(f2, f3);
        cv.u[2] = pack2(f4, f5);
        cv.u[3] = pack2(f6, f7);
        bf16x8 a = cv.v;
#pragma unroll
        for (int t = 0; t < 8; t++) {
            bf16x8 b = *(const bf16x8*)(wt + (t * 16 + m) * 136 + k0 + q * 8);
            acc[t] = __builtin_amdgcn_mfma_f32_16x16x32_bf16(a, b, acc[t], 0, 0, 0);
        }
    }

    int orow0 = row0 + q * 4;
#pragma unroll
    for (int t = 0; t < 8; t++) {
#pragma unroll
        for (int r = 0; r < 4; r++) {
            int rr = orow0 + r;
            if (rr < Nn) Yh[rr * Hh + t * 16 + m] = f2bf(acc[t][r]);
        }
    }
}

// ---------------- fused BN + mean pool + MLP head: 256 thr, split-row pool + split-k MLP ----------------
__global__ __launch_bounds__(256) void k_poolmlp(const u16* __restrict__ Ah,
                                                 const float* __restrict__ stats,
                                                 const float* __restrict__ gam,
                                                 const float* __restrict__ bet,
                                                 const int* __restrict__ gstart,
                                                 const float* __restrict__ W1,
                                                 const float* __restrict__ b1,
                                                 const float* __restrict__ W2,
                                                 const float* __restrict__ b2,
                                                 float* __restrict__ out) {
    int g = blockIdx.x;
    int t = threadIdx.x;
    int c = t & 127, h = t >> 7;          // h: row/k half
    __shared__ float pp[2][Hh];
    __shared__ float p[Hh];
    __shared__ float hpart[2][Hh];
    __shared__ float hid[Hh];

    float s0 = 0.f, s1 = 0.f;
#pragma unroll
    for (int r = 0; r < NREP; r++) {
        s0 += stats[r * 2 * Hh + c];
        s1 += stats[r * 2 * Hh + Hh + c];
    }
    float mu = s0 * (1.0f / Nn);
    float var = s1 * (1.0f / Nn) - mu * mu;
    float sc = rsqrtf(var + EPSf) * gam[c];
    float sf = bet[c] - mu * sc;

    int s = gstart[g], e = gstart[g + 1];
    float sum = 0.0f;
    for (int r = s + h; r < e; r += 2) {  // two row-halves in parallel
        float v = __uint_as_float((u32)Ah[r * Hh + c] << 16);
        sum += fmaxf(v * sc + sf, 0.0f);
    }
    pp[h][c] = sum;
    __syncthreads();
    if (h == 0) {
        int n = e - s;
        p[c] = (pp[0][c] + pp[1][c]) / (float)(n > 1 ? n : 1);
    }
    __syncthreads();
    float acc = (h == 0) ? b1[c] : 0.0f;  // split-k over W1
    for (int k = h * 64; k < h * 64 + 64; k++) acc += p[k] * W1[k * Hh + c];
    hpart[h][c] = acc;
    __syncthreads();
    if (h == 0) hid[c] = fmaxf(hpart[0][c] + hpart[1][c], 0.0f);
    __syncthreads();
    if (t < Cc) {
        float acc2 = b2[t];
        for (int k = 0; k < Hh; k++) acc2 += hid[k] * W2[k * Cc + t];
        out[g * Cc + t] = acc2;
    }
}

extern "C" void kernel_launch(void* const* d_in, const int* in_sizes, int n_in,
                              void* d_out, int out_size, void* d_ws, size_t ws_size,
                              hipStream_t stream) {
    const float* x      = (const float*)d_in[0];
    const int*   ei     = (const int*)d_in[1];
    const int*   batch  = (const int*)d_in[2];
    const float* conv_w = (const float*)d_in[3];
    const float* conv_b = (const float*)d_in[4];
    const float* bn_g   = (const float*)d_in[5];
    const float* bn_b   = (const float*)d_in[6];
    const float* w1     = (const float*)d_in[7];
    const float* b1     = (const float*)d_in[8];
    const float* w2     = (const float*)d_in[9];
    const float* b2     = (const float*)d_in[10];
    float* out = (float*)d_out;

    u16*   Yh      = (u16*)d_ws;                  // N*H bf16 row-major (gemm out)
    u16*   Ah      = Yh + Nn * Hh;                // N*H bf16 row-major (gather out)
    u16*   WT      = Ah + Nn * Hh;                // 3*H*H bf16 (W^T; slot 0 unused)
    float* dis     = (float*)(WT + 3 * Hh * Hh);  // N
    float* stats3  = dis + Nn;                    // 3 * STS (replica slabs)
    int*   rs      = (int*)(stats3 + 3 * STS);    // N+1 local-exclusive starts
    int*   rs2     = rs + Nn + 1;                 // N+1 globalized starts
    int*   gstart  = rs2 + Nn + 1;                // G+1
    int*   bsum    = gstart + Gg + 1;             // NSB
    u32*   recs    = (u32*)(bsum + NSB);          // E packed 4B records
    u16*   rankL   = (u16*)(recs + Ee);           // E within-(block,node) ranks
    u32*   partials = (u32*)(rankL + Ee);         // NBH * NW packed partial hists
    u32*   base_off = partials + NBH * NW;        // NBH * NW packed excl. offsets

    // ---- fused prologue: {hist || gemm0 || WT1/WT2+stats-zero}; CSR build ----
    k_pro<<<NBH + GT4 + 2, 1024, 50000, stream>>>(ei + Ee, rankL, partials, x,
                                                  conv_w, WT, stats3, Yh);
    k_scan1<<<NSB, 256, 0, stream>>>(partials, base_off, rs, bsum, dis, batch, gstart);
    k_fill<<<(Ee + 255) / 256, 256, 0, stream>>>(ei, rs, bsum, rs2, rankL, base_off,
                                                 dis, recs);

    for (int l = 0; l < 3; l++) {
        k_gather<<<2 * NGB, 256, 0, stream>>>(Yh, dis, conv_b + l * Hh, rs2,
                                              recs, Ah);
        k_stats<<<256, 256, 0, stream>>>(Ah, stats3 + l * STS);
        if (l < 2) {
            k_gemm<<<(Nn + 63) / 64, 256, 0, stream>>>(Ah, WT + (l + 1) * Hh * Hh, Yh,
                                                       stats3 + l * STS,
                                                       bn_g + l * Hh, bn_b + l * Hh);
        }
    }

    k_poolmlp<<<Gg, 256, 0, stream>>>(Ah, stats3 + 2 * STS, bn_g + 2 * Hh,
                                      bn_b + 2 * Hh, gstart, w1, b1, w2, b2, out);
}

// Round 12
// 291.449 us; speedup vs baseline: 1.1603x; 1.1603x over previous
//
#include <hip/hip_runtime.h>

#define Nn 50000
#define Ee 800000
#define Gg 1000
#define Hh 128
#define Cc 6
#define EPSf 1e-5f
#define SB 1024                       // elements per scan block
#define NSB ((Nn + SB - 1) / SB)      // 49
#define NBH 64                        // histogram blocks
#define EPB (Ee / NBH)                // 12500 edges per histogram block
#define NW (Nn / 2)                   // 25000 packed u16-pair words
#define HWH (NW / 2)                  // 12500 words per half-pass (50 KB LDS)
#define GT ((Nn + 63) / 64)           // 782 gemm tiles
#define GT4 ((GT + 3) / 4)            // 196 four-tile gemm groups
#define NREP 8                        // stats atomic-spread replicas
#define STS (NREP * 2 * Hh)           // 2048 floats per layer's stats slab

typedef unsigned short u16;
typedef unsigned int u32;
typedef __attribute__((ext_vector_type(8))) short bf16x8;
typedef __attribute__((ext_vector_type(4))) float f32x4;
typedef __attribute__((ext_vector_type(2))) float f32x2;   // packed-f32 (v_pk_fma_f32)
typedef __attribute__((ext_vector_type(4))) unsigned int u32x4;

static __device__ inline u16 f2bf(float f) {
    u32 u = __float_as_uint(f);
    u32 r = (u + 0x7fffu + ((u >> 16) & 1u)) >> 16;   // RNE
    return (u16)r;
}
static __device__ inline float bf_lo(u32 v) { return __uint_as_float(v << 16); }
static __device__ inline float bf_hi(u32 v) { return __uint_as_float(v & 0xffff0000u); }
static __device__ inline u32 pack2(float a, float b) {
    return ((u32)f2bf(b) << 16) | (u32)f2bf(a);
}

// ============ fused prologue: {hist} || {layer-0 GEMM (+W0 transpose)} || {WT1/WT2 + stats zero} ============
__global__ __launch_bounds__(1024) void k_pro(const int* __restrict__ ei_dst,
                                              u16* __restrict__ rankL,
                                              u32* __restrict__ partials,
                                              const float* __restrict__ Xf,
                                              const float* __restrict__ W3,
                                              u16* __restrict__ WT3,
                                              float* __restrict__ stats3,
                                              u16* __restrict__ Yh) {
    extern __shared__ __align__(16) unsigned char smem[];   // 50000 B dynamic
    int bid = blockIdx.x, tid = threadIdx.x;

    if (bid < NBH) {
        // ---- histogram branch (1024 threads) ----
        u32* h = (u32*)smem;          // HWH words (50 KB)
        int e0 = bid * EPB;
        u32* P = partials + bid * NW;
#pragma unroll 1
        for (int half = 0; half < 2; half++) {
            int wlo = half * HWH;
            for (int i = tid; i < HWH; i += 1024) h[i] = 0u;
            __syncthreads();
            for (int i = tid; i < EPB; i += 1024) {
                int d = ei_dst[e0 + i];
                int w = d >> 1;
                if (w >= wlo && w < wlo + HWH) {
                    u32 old = atomicAdd(&h[w - wlo], (d & 1) ? 65536u : 1u);
                    rankL[e0 + i] = (u16)((d & 1) ? (old >> 16) : (old & 0xffffu));
                }
            }
            __syncthreads();
            for (int i = tid; i < HWH; i += 1024) P[wlo + i] = h[i];
            __syncthreads();
        }
        return;
    }

    if (bid >= NBH + GT4) {
        // ---- WT1/WT2 transpose + stats zero branch ----
        int l = bid - (NBH + GT4) + 1;          // 1 or 2
        u16* tb = (u16*)smem;
        const float* W = W3 + l * Hh * Hh;
        u16* WTl = WT3 + l * Hh * Hh;
#pragma unroll
        for (int i = 0; i < 4; i++) {
            int v = tid + 1024 * i;             // float4 idx over 4096
            int r = v >> 5, c4 = v & 31;
            float4 d = ((const float4*)W)[v];
            u16* p = tb + r * 136 + c4 * 4;
            p[0] = f2bf(d.x); p[1] = f2bf(d.y); p[2] = f2bf(d.z); p[3] = f2bf(d.w);
        }
        if (l == 1) {
#pragma unroll
            for (int i = 0; i < 6; i++) {       // 3*STS = 6144 floats
                int idx = tid + 1024 * i;
                stats3[idx] = 0.0f;
            }
        }
        __syncthreads();
#pragma unroll
        for (int i = 0; i < 16; i++) {
            int o = tid + 1024 * i;             // u16 idx over 16384
            int n = o >> 7, k = o & 127;
            WTl[o] = tb[k * 136 + n];
        }
        return;
    }

    // ---- layer-0 GEMM branch: in-block W0 transpose, 4 tiles/block ----
    u16* wt = (u16*)smem;             // Hh*136 u16 = 34816 B
#pragma unroll
    for (int i = 0; i < 4; i++) {
        int v = tid + 1024 * i;       // float4 idx over 4096: W0[k][n0..n0+3]
        int k = v >> 5, n0 = (v & 31) << 2;
        float4 d = ((const float4*)W3)[v];
        wt[(n0 + 0) * 136 + k] = f2bf(d.x);
        wt[(n0 + 1) * 136 + k] = f2bf(d.y);
        wt[(n0 + 2) * 136 + k] = f2bf(d.z);
        wt[(n0 + 3) * 136 + k] = f2bf(d.w);
    }
    __syncthreads();

    int tile = (bid - NBH) * 4 + (tid >> 8);
    if (tile >= GT) return;
    int t256 = tid & 255;
    int wv = t256 >> 6, lane = t256 & 63;
    int m = lane & 15, q = lane >> 4;
    int row0 = tile * 64 + wv * 16;
    int lrow = row0 + m;
    if (lrow >= Nn) lrow = Nn - 1;    // clamp load row; stores guarded
    const float* xfrow = Xf + lrow * Hh + q * 8;

    f32x4 acc[8] = {};
#pragma unroll
    for (int k0 = 0; k0 < Hh; k0 += 32) {
        float4 u0 = *(const float4*)(xfrow + k0);
        float4 u1 = *(const float4*)(xfrow + k0 + 4);
        union { bf16x8 v; u32 u[4]; } cv;
        cv.u[0] = pack2(u0.x, u0.y);
        cv.u[1] = pack2(u0.z, u0.w);
        cv.u[2] = pack2(u1.x, u1.y);
        cv.u[3] = pack2(u1.z, u1.w);
        bf16x8 a = cv.v;
#pragma unroll
        for (int t = 0; t < 8; t++) {
            bf16x8 b = *(const bf16x8*)(wt + (t * 16 + m) * 136 + k0 + q * 8);
            acc[t] = __builtin_amdgcn_mfma_f32_16x16x32_bf16(a, b, acc[t], 0, 0, 0);
        }
    }

    int orow0 = row0 + q * 4;
#pragma unroll
    for (int t = 0; t < 8; t++) {
#pragma unroll
        for (int r = 0; r < 4; r++) {
            int rr = orow0 + r;
            if (rr < Nn) Yh[rr * Hh + t * 16 + m] = f2bf(acc[t][r]);
        }
    }
}

// ---------------- scan phase 1 (fused partials merge) + dis + gstart ----------------
__global__ __launch_bounds__(256) void k_scan1(const u32* __restrict__ partials,
                                               u32* __restrict__ base_off,
                                               int* __restrict__ rs,
                                               int* __restrict__ bsum,
                                               float* __restrict__ dis,
                                               const int* __restrict__ batch,
                                               int* __restrict__ gstart) {
    __shared__ int ts[256];
    int b = blockIdx.x;
    int t = threadIdx.x;
    int base = b * SB + t * 4;        // 4 nodes = 2 packed words
    int v[4] = {0, 0, 0, 0};
    if (base < Nn) {                  // Nn%4==0 so whole quad in-bounds
        int w0 = base >> 1;
        u32 run0 = 0, run1 = 0;
#pragma unroll 8
        for (int b2 = 0; b2 < NBH; b2++) {
            u32 p0 = partials[b2 * NW + w0];
            u32 p1 = partials[b2 * NW + w0 + 1];
            base_off[b2 * NW + w0] = run0;
            base_off[b2 * NW + w0 + 1] = run1;
            run0 += p0; run1 += p1;
        }
        v[0] = (int)(run0 & 0xffffu); v[1] = (int)(run0 >> 16);
        v[2] = (int)(run1 & 0xffffu); v[3] = (int)(run1 >> 16);
        dis[base]     = rsqrtf((float)v[0] + 1.0f);
        dis[base + 1] = rsqrtf((float)v[1] + 1.0f);
        dis[base + 2] = rsqrtf((float)v[2] + 1.0f);
        dis[base + 3] = rsqrtf((float)v[3] + 1.0f);
    }
    int g = b * 256 + t;
    if (g <= Gg) {
        int lo = 0, hi = Nn;
        while (lo < hi) {
            int mid = (lo + hi) >> 1;
            if (batch[mid] < g) lo = mid + 1; else hi = mid;
        }
        gstart[g] = lo;
    }
    int tsum = v[0] + v[1] + v[2] + v[3];
    ts[t] = tsum;
    __syncthreads();
    for (int off = 1; off < 256; off <<= 1) {
        int x = (t >= off) ? ts[t - off] : 0;
        __syncthreads();
        ts[t] += x;
        __syncthreads();
    }
    int run = (t == 0) ? 0 : ts[t - 1];
    if (t == 255) {
        bsum[b] = ts[255];
        if (b == NSB - 1) rs[Nn] = ts[255];   // local end of last block
    }
#pragma unroll
    for (int j = 0; j < 4; j++) {
        int i = base + j;
        if (i < Nn) { rs[i] = run; run += v[j]; }
    }
}

// ---------------- counting-sort fill (absorbs scan2): ATOMIC-FREE ----------------
__global__ __launch_bounds__(256) void k_fill(const int* __restrict__ ei,
                                              const int* __restrict__ rs,
                                              const int* __restrict__ bsum,
                                              int* __restrict__ rs2,
                                              const u16* __restrict__ rankL,
                                              const u32* __restrict__ base_off,
                                              const float* __restrict__ dis,
                                              u32* __restrict__ recs) {
    __shared__ int lboff[NSB];
    int t = threadIdx.x;
    if (t < 64) {
        int orig = (t < NSB) ? bsum[t] : 0;
        int v = orig;
#pragma unroll
        for (int off = 1; off < 64; off <<= 1) {
            int u = __shfl_up(v, off, 64);
            if (t >= off) v += u;
        }
        if (t < NSB) lboff[t] = v - orig;   // exclusive over scan blocks
    }
    __syncthreads();

    int gi = blockIdx.x * 256 + t;
    if (gi <= Nn) rs2[gi] = rs[gi] + lboff[gi >> 10];   // blocks 0..195 active here

    int e = gi;
    if (e >= Ee) return;
    int s = ei[e];
    int d = ei[Ee + e];
    int blk = e / EPB;
    u32 bo = base_off[blk * NW + (d >> 1)];
    int rank = (int)rankL[e] + (int)((d & 1) ? (bo >> 16) : (bo & 0xffffu));
    int slot = rs[d] + lboff[d >> 10] + rank;
    float w = dis[s] * dis[d];
    recs[slot] = ((u32)f2bf(w) << 16) | (u32)s;   // s < 50000 < 65536
}

// ---------------- CSR gather: single-pass, one wave/node, 4 edges per dwordx4 load ----------------
// Round-9 proven structure (best measured config). Accumulator as packed f32
// pairs so clang can lower the 8 FMAs per uint4 to 4 v_pk_fma_f32 (VOP3P).
// Per-channel FMA chains unchanged -> bit-identical numerics.
__global__ __launch_bounds__(256) void k_gather(const u16* __restrict__ Yh,
                                                const float* __restrict__ dis,
                                                const float* __restrict__ bias,
                                                const int* __restrict__ rs2,
                                                const u32* __restrict__ recs,
                                                u16* __restrict__ Ah) {
    int node = blockIdx.x * 4 + (threadIdx.x >> 6);
    if (node >= Nn) return;
    int lane = threadIdx.x & 63;
    int lg = lane >> 4;               // edge slot within quad
    int lc = lane & 15;               // uint4 column within row

    const uint4* rows4 = (const uint4*)Yh;    // row = 16 uint4 = 256 B

    f32x2 acc2[4] = {};               // 8 channels as 4 packed pairs

    int beg = rs2[node];
    int end = rs2[node + 1];

    for (int base = beg; base < end; base += 64) {
        int me = base + lane;
        u32 myrec = recs[me < end ? me : end - 1];   // one coalesced load / 64 edges
        int cnt = end - base;
        if (cnt > 64) cnt = 64;
        for (int i0 = 0; i0 < cnt; i0 += 16) {
            u32 rr[4]; f32x2 ww[4]; uint4 vv[4];
#pragma unroll
            for (int j = 0; j < 4; j++) {
                int si = i0 + j * 4 + lg;
                int sc = si < cnt ? si : cnt - 1;
                u32 rec = __shfl(myrec, sc, 64);
                rr[j] = rec & 0xffffu;
                float w = (si < cnt) ? __uint_as_float(rec & 0xffff0000u) : 0.0f;
                ww[j].x = w; ww[j].y = w;
            }
#pragma unroll
            for (int j = 0; j < 4; j++) vv[j] = rows4[rr[j] * 16 + lc];
#pragma unroll
            for (int j = 0; j < 4; j++) {
                f32x2 v0 = {bf_lo(vv[j].x), bf_hi(vv[j].x)};
                f32x2 v1 = {bf_lo(vv[j].y), bf_hi(vv[j].y)};
                f32x2 v2 = {bf_lo(vv[j].z), bf_hi(vv[j].z)};
                f32x2 v3 = {bf_lo(vv[j].w), bf_hi(vv[j].w)};
                acc2[0] += v0 * ww[j];
                acc2[1] += v1 * ww[j];
                acc2[2] += v2 * ww[j];
                acc2[3] += v3 * ww[j];
            }
        }
    }
    float acc[8] = {acc2[0].x, acc2[0].y, acc2[1].x, acc2[1].y,
                    acc2[2].x, acc2[2].y, acc2[3].x, acc2[3].y};
#pragma unroll
    for (int k = 0; k < 8; k++) {
        acc[k] += __shfl_xor(acc[k], 16, 64);
        acc[k] += __shfl_xor(acc[k], 32, 64);
    }
    if (lg == 0) {
        float sn = dis[node];
        sn = sn * sn;
        uint4 hv = rows4[node * 16 + lc];
        const float4* bq = (const float4*)bias;
        float4 b0 = bq[lc * 2];
        float4 b1 = bq[lc * 2 + 1];
        acc[0] = acc[0] + bf_lo(hv.x) * sn + b0.x;
        acc[1] = acc[1] + bf_hi(hv.x) * sn + b0.y;
        acc[2] = acc[2] + bf_lo(hv.y) * sn + b0.z;
        acc[3] = acc[3] + bf_hi(hv.y) * sn + b0.w;
        acc[4] = acc[4] + bf_lo(hv.z) * sn + b1.x;
        acc[5] = acc[5] + bf_hi(hv.z) * sn + b1.y;
        acc[6] = acc[6] + bf_lo(hv.w) * sn + b1.z;
        acc[7] = acc[7] + bf_hi(hv.w) * sn + b1.w;
        u32x4 o;
        o.x = pack2(acc[0], acc[1]);
        o.y = pack2(acc[2], acc[3]);
        o.z = pack2(acc[4], acc[5]);
        o.w = pack2(acc[6], acc[7]);
        __builtin_nontemporal_store(o, (u32x4*)Ah + node * 16 + lc);
    }
}

// ---------------- BN stats: per-channel sum & sumsq, 8-way replica atomic spread ----------------
__global__ __launch_bounds__(256) void k_stats(const u16* __restrict__ Ah,
                                               float* __restrict__ stats) {
    __shared__ float sh[4][256];
    int t = threadIdx.x;
    int jc = t & 63, ro = t >> 6;         // jc: u32-column (channels 2jc,2jc+1)
    const u32* col = (const u32*)Ah + jc;
    float sx = 0.f, sy = 0.f, qx = 0.f, qy = 0.f;
    for (int r = blockIdx.x * 16 + ro * 4; r < Nn; r += 4096) {
        u32 v[4];
#pragma unroll
        for (int k = 0; k < 4; k++) {
            int rr = r + k;
            v[k] = (rr < Nn) ? col[rr * 64] : 0u;
        }
#pragma unroll
        for (int k = 0; k < 4; k++) {
            float a = bf_lo(v[k]), b = bf_hi(v[k]);
            sx += a; sy += b; qx += a * a; qy += b * b;
        }
    }
    sh[0][t] = sx; sh[1][t] = sy; sh[2][t] = qx; sh[3][t] = qy;
    __syncthreads();
    if (t < 64) {
        sx = sh[0][t] + sh[0][t + 64] + sh[0][t + 128] + sh[0][t + 192];
        sy = sh[1][t] + sh[1][t + 64] + sh[1][t + 128] + sh[1][t + 192];
        qx = sh[2][t] + sh[2][t + 64] + sh[2][t + 128] + sh[2][t + 192];
        qy = sh[3][t] + sh[3][t + 64] + sh[3][t + 128] + sh[3][t + 192];
        float* rep = stats + (blockIdx.x & (NREP - 1)) * 2 * Hh;   // spread RMW lines 8x
        atomicAdd(&rep[2 * t], sx);
        atomicAdd(&rep[2 * t + 1], sy);
        atomicAdd(&rep[Hh + 2 * t], qx);
        atomicAdd(&rep[Hh + 2 * t + 1], qy);
    }
}

// ---------------- MFMA GEMM, fused BN-normalize+ReLU on A (layers 1,2) ----------------
__global__ __launch_bounds__(256) void k_gemm(const u16* __restrict__ Xin,
                                              const u16* __restrict__ WT,
                                              u16* __restrict__ Yh,
                                              const float* __restrict__ stats,
                                              const float* __restrict__ gam,
                                              const float* __restrict__ bet) {
    __shared__ u16 wt[Hh * 136];
    __shared__ float s_scale[Hh], s_shift[Hh];
    int tid = threadIdx.x;

    if (tid < Hh) {
        float s0 = 0.f, s1 = 0.f;
#pragma unroll
        for (int r = 0; r < NREP; r++) {          // sum replica slabs
            s0 += stats[r * 2 * Hh + tid];
            s1 += stats[r * 2 * Hh + Hh + tid];
        }
        float mu = s0 * (1.0f / Nn);
        float var = s1 * (1.0f / Nn) - mu * mu;
        float sc = rsqrtf(var + EPSf) * gam[tid];
        s_scale[tid] = sc;
        s_shift[tid] = bet[tid] - mu * sc;
    }
#pragma unroll
    for (int i = 0; i < 8; i++) {
        int v = tid + 256 * i;            // uint4 idx over 2048
        int n = v >> 4, k8 = v & 15;
        uint4 d = ((const uint4*)WT)[v];
        *((uint4*)(wt + n * 136 + k8 * 8)) = d;
    }
    __syncthreads();

    int wv = tid >> 6, lane = tid & 63;
    int m = lane & 15, q = lane >> 4;
    int row0 = blockIdx.x * 64 + wv * 16;
    int lrow = row0 + m;
    if (lrow >= Nn) lrow = Nn - 1;        // clamp load row; stores guarded
    const u16* xrow = Xin + lrow * Hh + q * 8;

    f32x4 acc[8] = {};
#pragma unroll
    for (int k0 = 0; k0 < Hh; k0 += 32) {
        int cb = k0 + q * 8;
        uint4 p = *(const uint4*)(xrow + k0);
        float4 sc0 = *(const float4*)(s_scale + cb);
        float4 sc1 = *(const float4*)(s_scale + cb + 4);
        float4 sh0 = *(const float4*)(s_shift + cb);
        float4 sh1 = *(const float4*)(s_shift + cb + 4);
        float f0 = fmaxf(bf_lo(p.x) * sc0.x + sh0.x, 0.0f);
        float f1 = fmaxf(bf_hi(p.x) * sc0.y + sh0.y, 0.0f);
        float f2 = fmaxf(bf_lo(p.y) * sc0.z + sh0.z, 0.0f);
        float f3 = fmaxf(bf_hi(p.y) * sc0.w + sh0.w, 0.0f);
        float f4 = fmaxf(bf_lo(p.z) * sc1.x + sh1.x, 0.0f);
        float f5 = fmaxf(bf_hi(p.z) * sc1.y + sh1.y, 0.0f);
        float f6 = fmaxf(bf_lo(p.w) * sc1.z + sh1.z, 0.0f);
        float f7 = fmaxf(bf_hi(p.w) * sc1.w + sh1.w, 0.0f);
        union { bf16x8 v; u32 u[4]; } cv;
        cv.u[0] = pack2(f0, f1);
        cv.u[1] = pack2(f2, f3);
        cv.u[2] = pack2(f4, f5);
        cv.u[3] = pack2(f6, f7);
        bf16x8 a = cv.v;
#pragma unroll
        for (int t = 0; t < 8; t++) {
            bf16x8 b = *(const bf16x8*)(wt + (t * 16 + m) * 136 + k0 + q * 8);
            acc[t] = __builtin_amdgcn_mfma_f32_16x16x32_bf16(a, b, acc[t], 0, 0, 0);
        }
    }

    int orow0 = row0 + q * 4;
#pragma unroll
    for (int t = 0; t < 8; t++) {
#pragma unroll
        for (int r = 0; r < 4; r++) {
            int rr = orow0 + r;
            if (rr < Nn) Yh[rr * Hh + t * 16 + m] = f2bf(acc[t][r]);
        }
    }
}

// ---------------- fused BN + mean pool + MLP head: 256 thr, split-row pool + split-k MLP ----------------
__global__ __launch_bounds__(256) void k_poolmlp(const u16* __restrict__ Ah,
                                                 const float* __restrict__ stats,
                                                 const float* __restrict__ gam,
                                                 const float* __restrict__ bet,
                                                 const int* __restrict__ gstart,
                                                 const float* __restrict__ W1,
                                                 const float* __restrict__ b1,
                                                 const float* __restrict__ W2,
                                                 const float* __restrict__ b2,
                                                 float* __restrict__ out) {
    int g = blockIdx.x;
    int t = threadIdx.x;
    int c = t & 127, h = t >> 7;          // h: row/k half
    __shared__ float pp[2][Hh];
    __shared__ float p[Hh];
    __shared__ float hpart[2][Hh];
    __shared__ float hid[Hh];

    float s0 = 0.f, s1 = 0.f;
#pragma unroll
    for (int r = 0; r < NREP; r++) {
        s0 += stats[r * 2 * Hh + c];
        s1 += stats[r * 2 * Hh + Hh + c];
    }
    float mu = s0 * (1.0f / Nn);
    float var = s1 * (1.0f / Nn) - mu * mu;
    float sc = rsqrtf(var + EPSf) * gam[c];
    float sf = bet[c] - mu * sc;

    int s = gstart[g], e = gstart[g + 1];
    float sum = 0.0f;
    for (int r = s + h; r < e; r += 2) {  // two row-halves in parallel
        float v = __uint_as_float((u32)Ah[r * Hh + c] << 16);
        sum += fmaxf(v * sc + sf, 0.0f);
    }
    pp[h][c] = sum;
    __syncthreads();
    if (h == 0) {
        int n = e - s;
        p[c] = (pp[0][c] + pp[1][c]) / (float)(n > 1 ? n : 1);
    }
    __syncthreads();
    float acc = (h == 0) ? b1[c] : 0.0f;  // split-k over W1
    for (int k = h * 64; k < h * 64 + 64; k++) acc += p[k] * W1[k * Hh + c];
    hpart[h][c] = acc;
    __syncthreads();
    if (h == 0) hid[c] = fmaxf(hpart[0][c] + hpart[1][c], 0.0f);
    __syncthreads();
    if (t < Cc) {
        float acc2 = b2[t];
        for (int k = 0; k < Hh; k++) acc2 += hid[k] * W2[k * Cc + t];
        out[g * Cc + t] = acc2;
    }
}

extern "C" void kernel_launch(void* const* d_in, const int* in_sizes, int n_in,
                              void* d_out, int out_size, void* d_ws, size_t ws_size,
                              hipStream_t stream) {
    const float* x      = (const float*)d_in[0];
    const int*   ei     = (const int*)d_in[1];
    const int*   batch  = (const int*)d_in[2];
    const float* conv_w = (const float*)d_in[3];
    const float* conv_b = (const float*)d_in[4];
    const float* bn_g   = (const float*)d_in[5];
    const float* bn_b   = (const float*)d_in[6];
    const float* w1     = (const float*)d_in[7];
    const float* b1     = (const float*)d_in[8];
    const float* w2     = (const float*)d_in[9];
    const float* b2     = (const float*)d_in[10];
    float* out = (float*)d_out;

    u16*   Yh      = (u16*)d_ws;                  // N*H bf16 row-major (gemm out)
    u16*   Ah      = Yh + Nn * Hh;                // N*H bf16 row-major (gather out)
    u16*   WT      = Ah + Nn * Hh;                // 3*H*H bf16 (W^T; slot 0 unused)
    float* dis     = (float*)(WT + 3 * Hh * Hh);  // N
    float* stats3  = dis + Nn;                    // 3 * STS (replica slabs)
    int*   rs      = (int*)(stats3 + 3 * STS);    // N+1 local-exclusive starts
    int*   rs2     = rs + Nn + 1;                 // N+1 globalized starts
    int*   gstart  = rs2 + Nn + 1;                // G+1
    int*   bsum    = gstart + Gg + 1;             // NSB
    u32*   recs    = (u32*)(bsum + NSB);          // E packed 4B records
    u16*   rankL   = (u16*)(recs + Ee);           // E within-(block,node) ranks
    u32*   partials = (u32*)(rankL + Ee);         // NBH * NW packed partial hists
    u32*   base_off = partials + NBH * NW;        // NBH * NW packed excl. offsets

    // ---- fused prologue: {hist || gemm0 || WT1/WT2+stats-zero}; CSR build ----
    k_pro<<<NBH + GT4 + 2, 1024, 50000, stream>>>(ei + Ee, rankL, partials, x,
                                                  conv_w, WT, stats3, Yh);
    k_scan1<<<NSB, 256, 0, stream>>>(partials, base_off, rs, bsum, dis, batch, gstart);
    k_fill<<<(Ee + 255) / 256, 256, 0, stream>>>(ei, rs, bsum, rs2, rankL, base_off,
                                                 dis, recs);

    for (int l = 0; l < 3; l++) {
        k_gather<<<(Nn + 3) / 4, 256, 0, stream>>>(Yh, dis, conv_b + l * Hh, rs2,
                                                   recs, Ah);
        k_stats<<<256, 256, 0, stream>>>(Ah, stats3 + l * STS);
        if (l < 2) {
            k_gemm<<<(Nn + 63) / 64, 256, 0, stream>>>(Ah, WT + (l + 1) * Hh * Hh, Yh,
                                                       stats3 + l * STS,
                                                       bn_g + l * Hh, bn_b + l * Hh);
        }
    }

    k_poolmlp<<<Gg, 256, 0, stream>>>(Ah, stats3 + 2 * STS, bn_g + 2 * Hh,
                                      bn_b + 2 * Hh, gstart, w1, b1, w2, b2, out);
}

// Round 14
// 289.310 us; speedup vs baseline: 1.1688x; 1.0074x over previous
//
#include <hip/hip_runtime.h>

#define Nn 50000
#define Ee 800000
#define Gg 1000
#define Hh 128
#define Cc 6
#define EPSf 1e-5f
#define SB 1024                       // elements per scan block
#define NSB ((Nn + SB - 1) / SB)      // 49
#define NBH 64                        // histogram blocks
#define EPB (Ee / NBH)                // 12500 edges per histogram block
#define NW (Nn / 2)                   // 25000 packed u16-pair words
#define HWH (NW / 2)                  // 12500 words per half-pass (50 KB LDS)
#define GT ((Nn + 63) / 64)           // 782 gemm tiles
#define GT4 ((GT + 3) / 4)            // 196 four-tile gemm groups
#define NREP 8                        // stats atomic-spread replicas
#define STS (NREP * 2 * Hh)           // 2048 floats per layer's stats slab

typedef unsigned short u16;
typedef unsigned int u32;
typedef _Float16 f16;
typedef __attribute__((ext_vector_type(8))) _Float16 f16x8;
typedef __attribute__((ext_vector_type(4))) float f32x4;
typedef __attribute__((ext_vector_type(4))) unsigned int u32x4;

// bf16 only for the recs edge-weight trick (weight in high 16 bits of a u32)
static __device__ inline u16 f2bf(float f) {
    u32 u = __float_as_uint(f);
    u32 r = (u + 0x7fffu + ((u >> 16) & 1u)) >> 16;   // RNE
    return (u16)r;
}
// f16 activation path: v_cvt_f16_f32 / v_cvt_pkrtz_f16_f32 / v_cvt_f32_f16 (+op_sel)
static __device__ inline u16 f2h(float f) {
    f16 h = (f16)f;
    return __builtin_bit_cast(u16, h);
}
static __device__ inline u32 pack2h(float a, float b) {
    auto h = __builtin_amdgcn_cvt_pkrtz(a, b);   // __fp16 ext_vector(2): bit_cast, don't retype
    return __builtin_bit_cast(u32, h);
}
static __device__ inline float h_lo(u32 v) {
    u16 x = (u16)v;
    return (float)__builtin_bit_cast(f16, x);
}
static __device__ inline float h_hi(u32 v) {
    u16 x = (u16)(v >> 16);
    return (float)__builtin_bit_cast(f16, x);
}
static __device__ inline float h1(u16 x) {
    return (float)__builtin_bit_cast(f16, x);
}

// ============ fused prologue: {hist} || {layer-0 GEMM (+W0 transpose)} || {WT1/WT2 + stats zero} ============
__global__ __launch_bounds__(1024) void k_pro(const int* __restrict__ ei_dst,
                                              u16* __restrict__ rankL,
                                              u32* __restrict__ partials,
                                              const float* __restrict__ Xf,
                                              const float* __restrict__ W3,
                                              u16* __restrict__ WT3,
                                              float* __restrict__ stats3,
                                              u16* __restrict__ Yh) {
    extern __shared__ __align__(16) unsigned char smem[];   // 50000 B dynamic
    int bid = blockIdx.x, tid = threadIdx.x;

    if (bid < NBH) {
        // ---- histogram branch (1024 threads) ----
        u32* h = (u32*)smem;          // HWH words (50 KB)
        int e0 = bid * EPB;
        u32* P = partials + bid * NW;
#pragma unroll 1
        for (int half = 0; half < 2; half++) {
            int wlo = half * HWH;
            for (int i = tid; i < HWH; i += 1024) h[i] = 0u;
            __syncthreads();
            for (int i = tid; i < EPB; i += 1024) {
                int d = ei_dst[e0 + i];
                int w = d >> 1;
                if (w >= wlo && w < wlo + HWH) {
                    u32 old = atomicAdd(&h[w - wlo], (d & 1) ? 65536u : 1u);
                    rankL[e0 + i] = (u16)((d & 1) ? (old >> 16) : (old & 0xffffu));
                }
            }
            __syncthreads();
            for (int i = tid; i < HWH; i += 1024) P[wlo + i] = h[i];
            __syncthreads();
        }
        return;
    }

    if (bid >= NBH + GT4) {
        // ---- WT1/WT2 transpose (f16) + stats zero branch ----
        int l = bid - (NBH + GT4) + 1;          // 1 or 2
        u16* tb = (u16*)smem;
        const float* W = W3 + l * Hh * Hh;
        u16* WTl = WT3 + l * Hh * Hh;
#pragma unroll
        for (int i = 0; i < 4; i++) {
            int v = tid + 1024 * i;             // float4 idx over 4096
            int r = v >> 5, c4 = v & 31;
            float4 d = ((const float4*)W)[v];
            u16* p = tb + r * 136 + c4 * 4;
            p[0] = f2h(d.x); p[1] = f2h(d.y); p[2] = f2h(d.z); p[3] = f2h(d.w);
        }
        if (l == 1) {
#pragma unroll
            for (int i = 0; i < 6; i++) {       // 3*STS = 6144 floats
                int idx = tid + 1024 * i;
                stats3[idx] = 0.0f;
            }
        }
        __syncthreads();
#pragma unroll
        for (int i = 0; i < 16; i++) {
            int o = tid + 1024 * i;             // u16 idx over 16384
            int n = o >> 7, k = o & 127;
            WTl[o] = tb[k * 136 + n];
        }
        return;
    }

    // ---- layer-0 GEMM branch: in-block W0 transpose (f16), 4 tiles/block ----
    u16* wt = (u16*)smem;             // Hh*136 u16 = 34816 B
#pragma unroll
    for (int i = 0; i < 4; i++) {
        int v = tid + 1024 * i;       // float4 idx over 4096: W0[k][n0..n0+3]
        int k = v >> 5, n0 = (v & 31) << 2;
        float4 d = ((const float4*)W3)[v];
        wt[(n0 + 0) * 136 + k] = f2h(d.x);
        wt[(n0 + 1) * 136 + k] = f2h(d.y);
        wt[(n0 + 2) * 136 + k] = f2h(d.z);
        wt[(n0 + 3) * 136 + k] = f2h(d.w);
    }
    __syncthreads();

    int tile = (bid - NBH) * 4 + (tid >> 8);
    if (tile >= GT) return;
    int t256 = tid & 255;
    int wv = t256 >> 6, lane = t256 & 63;
    int m = lane & 15, q = lane >> 4;
    int row0 = tile * 64 + wv * 16;
    int lrow = row0 + m;
    if (lrow >= Nn) lrow = Nn - 1;    // clamp load row; stores guarded
    const float* xfrow = Xf + lrow * Hh + q * 8;

    f32x4 acc[8] = {};
#pragma unroll
    for (int k0 = 0; k0 < Hh; k0 += 32) {
        float4 u0 = *(const float4*)(xfrow + k0);
        float4 u1 = *(const float4*)(xfrow + k0 + 4);
        union { f16x8 v; u32 u[4]; } cv;
        cv.u[0] = pack2h(u0.x, u0.y);
        cv.u[1] = pack2h(u0.z, u0.w);
        cv.u[2] = pack2h(u1.x, u1.y);
        cv.u[3] = pack2h(u1.z, u1.w);
        f16x8 a = cv.v;
#pragma unroll
        for (int t = 0; t < 8; t++) {
            f16x8 b = *(const f16x8*)(wt + (t * 16 + m) * 136 + k0 + q * 8);
            acc[t] = __builtin_amdgcn_mfma_f32_16x16x32_f16(a, b, acc[t], 0, 0, 0);
        }
    }

    int orow0 = row0 + q * 4;
#pragma unroll
    for (int t = 0; t < 8; t++) {
#pragma unroll
        for (int r = 0; r < 4; r++) {
            int rr = orow0 + r;
            if (rr < Nn) Yh[rr * Hh + t * 16 + m] = f2h(acc[t][r]);
        }
    }
}

// ---------------- scan phase 1 (fused partials merge) + dis + gstart ----------------
__global__ __launch_bounds__(256) void k_scan1(const u32* __restrict__ partials,
                                               u32* __restrict__ base_off,
                                               int* __restrict__ rs,
                                               int* __restrict__ bsum,
                                               float* __restrict__ dis,
                                               const int* __restrict__ batch,
                                               int* __restrict__ gstart) {
    __shared__ int ts[256];
    int b = blockIdx.x;
    int t = threadIdx.x;
    int base = b * SB + t * 4;        // 4 nodes = 2 packed words
    int v[4] = {0, 0, 0, 0};
    if (base < Nn) {                  // Nn%4==0 so whole quad in-bounds
        int w0 = base >> 1;
        u32 run0 = 0, run1 = 0;
#pragma unroll 8
        for (int b2 = 0; b2 < NBH; b2++) {
            u32 p0 = partials[b2 * NW + w0];
            u32 p1 = partials[b2 * NW + w0 + 1];
            base_off[b2 * NW + w0] = run0;
            base_off[b2 * NW + w0 + 1] = run1;
            run0 += p0; run1 += p1;
        }
        v[0] = (int)(run0 & 0xffffu); v[1] = (int)(run0 >> 16);
        v[2] = (int)(run1 & 0xffffu); v[3] = (int)(run1 >> 16);
        dis[base]     = rsqrtf((float)v[0] + 1.0f);
        dis[base + 1] = rsqrtf((float)v[1] + 1.0f);
        dis[base + 2] = rsqrtf((float)v[2] + 1.0f);
        dis[base + 3] = rsqrtf((float)v[3] + 1.0f);
    }
    int g = b * 256 + t;
    if (g <= Gg) {
        int lo = 0, hi = Nn;
        while (lo < hi) {
            int mid = (lo + hi) >> 1;
            if (batch[mid] < g) lo = mid + 1; else hi = mid;
        }
        gstart[g] = lo;
    }
    int tsum = v[0] + v[1] + v[2] + v[3];
    ts[t] = tsum;
    __syncthreads();
    for (int off = 1; off < 256; off <<= 1) {
        int x = (t >= off) ? ts[t - off] : 0;
        __syncthreads();
        ts[t] += x;
        __syncthreads();
    }
    int run = (t == 0) ? 0 : ts[t - 1];
    if (t == 255) {
        bsum[b] = ts[255];
        if (b == NSB - 1) rs[Nn] = ts[255];   // local end of last block
    }
#pragma unroll
    for (int j = 0; j < 4; j++) {
        int i = base + j;
        if (i < Nn) { rs[i] = run; run += v[j]; }
    }
}

// ---------------- counting-sort fill (absorbs scan2): ATOMIC-FREE ----------------
__global__ __launch_bounds__(256) void k_fill(const int* __restrict__ ei,
                                              const int* __restrict__ rs,
                                              const int* __restrict__ bsum,
                                              int* __restrict__ rs2,
                                              const u16* __restrict__ rankL,
                                              const u32* __restrict__ base_off,
                                              const float* __restrict__ dis,
                                              u32* __restrict__ recs) {
    __shared__ int lboff[NSB];
    int t = threadIdx.x;
    if (t < 64) {
        int orig = (t < NSB) ? bsum[t] : 0;
        int v = orig;
#pragma unroll
        for (int off = 1; off < 64; off <<= 1) {
            int u = __shfl_up(v, off, 64);
            if (t >= off) v += u;
        }
        if (t < NSB) lboff[t] = v - orig;   // exclusive over scan blocks
    }
    __syncthreads();

    int gi = blockIdx.x * 256 + t;
    if (gi <= Nn) rs2[gi] = rs[gi] + lboff[gi >> 10];   // blocks 0..195 active here

    int e = gi;
    if (e >= Ee) return;
    int s = ei[e];
    int d = ei[Ee + e];
    int blk = e / EPB;
    u32 bo = base_off[blk * NW + (d >> 1)];
    int rank = (int)rankL[e] + (int)((d & 1) ? (bo >> 16) : (bo & 0xffffu));
    int slot = rs[d] + lboff[d >> 10] + rank;
    float w = dis[s] * dis[d];
    recs[slot] = ((u32)f2bf(w) << 16) | (u32)s;   // s < 50000 < 65536
}

// ---------------- CSR gather: single-pass, one wave/node, 4 edges per dwordx4 load ----------------
// Round-9 proven structure; activations are f16 so each channel update is one
// v_fma_mix_f32 (f16 src converted inside the FMA) -- deletes the 8 explicit
// bf16->f32 shift/and converts per uint4 that made this kernel VALU-bound.
__global__ __launch_bounds__(256) void k_gather(const u16* __restrict__ Yh,
                                                const float* __restrict__ dis,
                                                const float* __restrict__ bias,
                                                const int* __restrict__ rs2,
                                                const u32* __restrict__ recs,
                                                u16* __restrict__ Ah) {
    int node = blockIdx.x * 4 + (threadIdx.x >> 6);
    if (node >= Nn) return;
    int lane = threadIdx.x & 63;
    int lg = lane >> 4;               // edge slot within quad
    int lc = lane & 15;               // uint4 column within row

    const uint4* rows4 = (const uint4*)Yh;    // row = 16 uint4 = 256 B

    float acc[8] = {0.f, 0.f, 0.f, 0.f, 0.f, 0.f, 0.f, 0.f};

    int beg = rs2[node];
    int end = rs2[node + 1];

    for (int base = beg; base < end; base += 64) {
        int me = base + lane;
        u32 myrec = recs[me < end ? me : end - 1];   // one coalesced load / 64 edges
        int cnt = end - base;
        if (cnt > 64) cnt = 64;
        for (int i0 = 0; i0 < cnt; i0 += 16) {
            u32 rr[4]; float ww[4]; uint4 vv[4];
#pragma unroll
            for (int j = 0; j < 4; j++) {
                int si = i0 + j * 4 + lg;
                int sc = si < cnt ? si : cnt - 1;
                u32 rec = __shfl(myrec, sc, 64);
                rr[j] = rec & 0xffffu;
                ww[j] = (si < cnt) ? __uint_as_float(rec & 0xffff0000u) : 0.0f;
            }
#pragma unroll
            for (int j = 0; j < 4; j++) vv[j] = rows4[rr[j] * 16 + lc];
#pragma unroll
            for (int j = 0; j < 4; j++) {
                acc[0] += h_lo(vv[j].x) * ww[j];
                acc[1] += h_hi(vv[j].x) * ww[j];
                acc[2] += h_lo(vv[j].y) * ww[j];
                acc[3] += h_hi(vv[j].y) * ww[j];
                acc[4] += h_lo(vv[j].z) * ww[j];
                acc[5] += h_hi(vv[j].z) * ww[j];
                acc[6] += h_lo(vv[j].w) * ww[j];
                acc[7] += h_hi(vv[j].w) * ww[j];
            }
        }
    }
#pragma unroll
    for (int k = 0; k < 8; k++) {
        acc[k] += __shfl_xor(acc[k], 16, 64);
        acc[k] += __shfl_xor(acc[k], 32, 64);
    }
    if (lg == 0) {
        float sn = dis[node];
        sn = sn * sn;
        uint4 hv = rows4[node * 16 + lc];
        const float4* bq = (const float4*)bias;
        float4 b0 = bq[lc * 2];
        float4 b1 = bq[lc * 2 + 1];
        acc[0] = acc[0] + h_lo(hv.x) * sn + b0.x;
        acc[1] = acc[1] + h_hi(hv.x) * sn + b0.y;
        acc[2] = acc[2] + h_lo(hv.y) * sn + b0.z;
        acc[3] = acc[3] + h_hi(hv.y) * sn + b0.w;
        acc[4] = acc[4] + h_lo(hv.z) * sn + b1.x;
        acc[5] = acc[5] + h_hi(hv.z) * sn + b1.y;
        acc[6] = acc[6] + h_lo(hv.w) * sn + b1.z;
        acc[7] = acc[7] + h_hi(hv.w) * sn + b1.w;
        u32x4 o;
        o.x = pack2h(acc[0], acc[1]);
        o.y = pack2h(acc[2], acc[3]);
        o.z = pack2h(acc[4], acc[5]);
        o.w = pack2h(acc[6], acc[7]);
        __builtin_nontemporal_store(o, (u32x4*)Ah + node * 16 + lc);
    }
}

// ---------------- BN stats: per-channel sum & sumsq, 8-way replica atomic spread ----------------
__global__ __launch_bounds__(256) void k_stats(const u16* __restrict__ Ah,
                                               float* __restrict__ stats) {
    __shared__ float sh[4][256];
    int t = threadIdx.x;
    int jc = t & 63, ro = t >> 6;         // jc: u32-column (channels 2jc,2jc+1)
    const u32* col = (const u32*)Ah + jc;
    float sx = 0.f, sy = 0.f, qx = 0.f, qy = 0.f;
    for (int r = blockIdx.x * 16 + ro * 4; r < Nn; r += 4096) {
        u32 v[4];
#pragma unroll
        for (int k = 0; k < 4; k++) {
            int rr = r + k;
            v[k] = (rr < Nn) ? col[rr * 64] : 0u;
        }
#pragma unroll
        for (int k = 0; k < 4; k++) {
            float a = h_lo(v[k]), b = h_hi(v[k]);
            sx += a; sy += b; qx += a * a; qy += b * b;
        }
    }
    sh[0][t] = sx; sh[1][t] = sy; sh[2][t] = qx; sh[3][t] = qy;
    __syncthreads();
    if (t < 64) {
        sx = sh[0][t] + sh[0][t + 64] + sh[0][t + 128] + sh[0][t + 192];
        sy = sh[1][t] + sh[1][t + 64] + sh[1][t + 128] + sh[1][t + 192];
        qx = sh[2][t] + sh[2][t + 64] + sh[2][t + 128] + sh[2][t + 192];
        qy = sh[3][t] + sh[3][t + 64] + sh[3][t + 128] + sh[3][t + 192];
        float* rep = stats + (blockIdx.x & (NREP - 1)) * 2 * Hh;   // spread RMW lines 8x
        atomicAdd(&rep[2 * t], sx);
        atomicAdd(&rep[2 * t + 1], sy);
        atomicAdd(&rep[Hh + 2 * t], qx);
        atomicAdd(&rep[Hh + 2 * t + 1], qy);
    }
}

// ---------------- MFMA GEMM (f16), fused BN-normalize+ReLU on A (layers 1,2) ----------------
__global__ __launch_bounds__(256) void k_gemm(const u16* __restrict__ Xin,
                                              const u16* __restrict__ WT,
                                              u16* __restrict__ Yh,
                                              const float* __restrict__ stats,
                                              const float* __restrict__ gam,
                                              const float* __restrict__ bet) {
    __shared__ u16 wt[Hh * 136];
    __shared__ float s_scale[Hh], s_shift[Hh];
    int tid = threadIdx.x;

    if (tid < Hh) {
        float s0 = 0.f, s1 = 0.f;
#pragma unroll
        for (int r = 0; r < NREP; r++) {          // sum replica slabs
            s0 += stats[r * 2 * Hh + tid];
            s1 += stats[r * 2 * Hh + Hh + tid];
        }
        float mu = s0 * (1.0f / Nn);
        float var = s1 * (1.0f / Nn) - mu * mu;
        float sc = rsqrtf(var + EPSf) * gam[tid];
        s_scale[tid] = sc;
        s_shift[tid] = bet[tid] - mu * sc;
    }
#pragma unroll
    for (int i = 0; i < 8; i++) {
        int v = tid + 256 * i;            // uint4 idx over 2048
        int n = v >> 4, k8 = v & 15;
        uint4 d = ((const uint4*)WT)[v];
        *((uint4*)(wt + n * 136 + k8 * 8)) = d;
    }
    __syncthreads();

    int wv = tid >> 6, lane = tid & 63;
    int m = lane & 15, q = lane >> 4;
    int row0 = blockIdx.x * 64 + wv * 16;
    int lrow = row0 + m;
    if (lrow >= Nn) lrow = Nn - 1;        // clamp load row; stores guarded
    const u16* xrow = Xin + lrow * Hh + q * 8;

    f32x4 acc[8] = {};
#pragma unroll
    for (int k0 = 0; k0 < Hh; k0 += 32) {
        int cb = k0 + q * 8;
        uint4 p = *(const uint4*)(xrow + k0);
        float4 sc0 = *(const float4*)(s_scale + cb);
        float4 sc1 = *(const float4*)(s_scale + cb + 4);
        float4 sh0 = *(const float4*)(s_shift + cb);
        float4 sh1 = *(const float4*)(s_shift + cb + 4);
        float f0 = fmaxf(h_lo(p.x) * sc0.x + sh0.x, 0.0f);
        float f1 = fmaxf(h_hi(p.x) * sc0.y + sh0.y, 0.0f);
        float f2 = fmaxf(h_lo(p.y) * sc0.z + sh0.z, 0.0f);
        float f3 = fmaxf(h_hi(p.y) * sc0.w + sh0.w, 0.0f);
        float f4 = fmaxf(h_lo(p.z) * sc1.x + sh1.x, 0.0f);
        float f5 = fmaxf(h_hi(p.z) * sc1.y + sh1.y, 0.0f);
        float f6 = fmaxf(h_lo(p.w) * sc1.z + sh1.z, 0.0f);
        float f7 = fmaxf(h_hi(p.w) * sc1.w + sh1.w, 0.0f);
        union { f16x8 v; u32 u[4]; } cv;
        cv.u[0] = pack2h(f0, f1);
        cv.u[1] = pack2h(f2, f3);
        cv.u[2] = pack2h(f4, f5);
        cv.u[3] = pack2h(f6, f7);
        f16x8 a = cv.v;
#pragma unroll
        for (int t = 0; t < 8; t++) {
            f16x8 b = *(const f16x8*)(wt + (t * 16 + m) * 136 + k0 + q * 8);
            acc[t] = __builtin_amdgcn_mfma_f32_16x16x32_f16(a, b, acc[t], 0, 0, 0);
        }
    }

    int orow0 = row0 + q * 4;
#pragma unroll
    for (int t = 0; t < 8; t++) {
#pragma unroll
        for (int r = 0; r < 4; r++) {
            int rr = orow0 + r;
            if (rr < Nn) Yh[rr * Hh + t * 16 + m] = f2h(acc[t][r]);
        }
    }
}

// ---------------- fused BN + mean pool + MLP head: 256 thr, split-row pool + split-k MLP ----------------
__global__ __launch_bounds__(256) void k_poolmlp(const u16* __restrict__ Ah,
                                                 const float* __restrict__ stats,
                                                 const float* __restrict__ gam,
                                                 const float* __restrict__ bet,
                                                 const int* __restrict__ gstart,
                                                 const float* __restrict__ W1,
                                                 const float* __restrict__ b1,
                                                 const float* __restrict__ W2,
                                                 const float* __restrict__ b2,
                                                 float* __restrict__ out) {
    int g = blockIdx.x;
    int t = threadIdx.x;
    int c = t & 127, h = t >> 7;          // h: row/k half
    __shared__ float pp[2][Hh];
    __shared__ float p[Hh];
    __shared__ float hpart[2][Hh];
    __shared__ float hid[Hh];

    float s0 = 0.f, s1 = 0.f;
#pragma unroll
    for (int r = 0; r < NREP; r++) {
        s0 += stats[r * 2 * Hh + c];
        s1 += stats[r * 2 * Hh + Hh + c];
    }
    float mu = s0 * (1.0f / Nn);
    float var = s1 * (1.0f / Nn) - mu * mu;
    float sc = rsqrtf(var + EPSf) * gam[c];
    float sf = bet[c] - mu * sc;

    int s = gstart[g], e = gstart[g + 1];
    float sum = 0.0f;
    for (int r = s + h; r < e; r += 2) {  // two row-halves in parallel
        float v = h1(Ah[r * Hh + c]);
        sum += fmaxf(v * sc + sf, 0.0f);
    }
    pp[h][c] = sum;
    __syncthreads();
    if (h == 0) {
        int n = e - s;
        p[c] = (pp[0][c] + pp[1][c]) / (float)(n > 1 ? n : 1);
    }
    __syncthreads();
    float acc = (h == 0) ? b1[c] : 0.0f;  // split-k over W1
    for (int k = h * 64; k < h * 64 + 64; k++) acc += p[k] * W1[k * Hh + c];
    hpart[h][c] = acc;
    __syncthreads();
    if (h == 0) hid[c] = fmaxf(hpart[0][c] + hpart[1][c], 0.0f);
    __syncthreads();
    if (t < Cc) {
        float acc2 = b2[t];
        for (int k = 0; k < Hh; k++) acc2 += hid[k] * W2[k * Cc + t];
        out[g * Cc + t] = acc2;
    }
}

extern "C" void kernel_launch(void* const* d_in, const int* in_sizes, int n_in,
                              void* d_out, int out_size, void* d_ws, size_t ws_size,
                              hipStream_t stream) {
    const float* x      = (const float*)d_in[0];
    const int*   ei     = (const int*)d_in[1];
    const int*   batch  = (const int*)d_in[2];
    const float* conv_w = (const float*)d_in[3];
    const float* conv_b = (const float*)d_in[4];
    const float* bn_g   = (const float*)d_in[5];
    const float* bn_b   = (const float*)d_in[6];
    const float* w1     = (const float*)d_in[7];
    const float* b1     = (const float*)d_in[8];
    const float* w2     = (const float*)d_in[9];
    const float* b2     = (const float*)d_in[10];
    float* out = (float*)d_out;

    u16*   Yh      = (u16*)d_ws;                  // N*H f16 row-major (gemm out)
    u16*   Ah      = Yh + Nn * Hh;                // N*H f16 row-major (gather out)
    u16*   WT      = Ah + Nn * Hh;                // 3*H*H f16 (W^T; slot 0 unused)
    float* dis     = (float*)(WT + 3 * Hh * Hh);  // N
    float* stats3  = dis + Nn;                    // 3 * STS (replica slabs)
    int*   rs      = (int*)(stats3 + 3 * STS);    // N+1 local-exclusive starts
    int*   rs2     = rs + Nn + 1;                 // N+1 globalized starts
    int*   gstart  = rs2 + Nn + 1;                // G+1
    int*   bsum    = gstart + Gg + 1;             // NSB
    u32*   recs    = (u32*)(bsum + NSB);          // E packed 4B records
    u16*   rankL   = (u16*)(recs + Ee);           // E within-(block,node) ranks
    u32*   partials = (u32*)(rankL + Ee);         // NBH * NW packed partial hists
    u32*   base_off = partials + NBH * NW;        // NBH * NW packed excl. offsets

    // ---- fused prologue: {hist || gemm0 || WT1/WT2+stats-zero}; CSR build ----
    k_pro<<<NBH + GT4 + 2, 1024, 50000, stream>>>(ei + Ee, rankL, partials, x,
                                                  conv_w, WT, stats3, Yh);
    k_scan1<<<NSB, 256, 0, stream>>>(partials, base_off, rs, bsum, dis, batch, gstart);
    k_fill<<<(Ee + 255) / 256, 256, 0, stream>>>(ei, rs, bsum, rs2, rankL, base_off,
                                                 dis, recs);

    for (int l = 0; l < 3; l++) {
        k_gather<<<(Nn + 3) / 4, 256, 0, stream>>>(Yh, dis, conv_b + l * Hh, rs2,
                                                   recs, Ah);
        k_stats<<<256, 256, 0, stream>>>(Ah, stats3 + l * STS);
        if (l < 2) {
            k_gemm<<<(Nn + 63) / 64, 256, 0, stream>>>(Ah, WT + (l + 1) * Hh * Hh, Yh,
                                                       stats3 + l * STS,
                                                       bn_g + l * Hh, bn_b + l * Hh);
        }
    }

    k_poolmlp<<<Gg, 256, 0, stream>>>(Ah, stats3 + 2 * STS, bn_g + 2 * Hh,
                                      bn_b + 2 * Hh, gstart, w1, b1, w2, b2, out);
}